// Round 6
// baseline (151.923 us; speedup 1.0000x reference)
//
#include <hip/hip_runtime.h>
#include <cstdint>
#include <cstddef>

// ---------------------------------------------------------------------------
// MultiHeadAttention (B=2, S=2048, DIM=1024, H=16, HD=64), causal + RoPE.
// R5 (resubmit after infra failure): 4 launches total.
//   k_prep     : fp32->bf16 x5 + rope cos/sin table, one launch
//   k_gemm_qkv : fused QKV projections; epilogue applies RoPE (Q scaled 1/8,
//                K unscaled) via shfl_xor pair exchange, and writes V
//                transposed straight into VT[bh][d][s]
//   k_attn     : paired causal flash attn, in-wave pipelined (QKT(t+1)
//                overlaps softmax(t)), V triple-buffered, counted vmcnt
//   k_gemm_out : out projection, fp32 + bias into d_out
// ---------------------------------------------------------------------------

typedef __bf16 bf16_t;
typedef __bf16 bf16x8 __attribute__((ext_vector_type(8)));
typedef __bf16 bf16x4 __attribute__((ext_vector_type(4)));
typedef float  f32x4  __attribute__((ext_vector_type(4)));

#define DEVFN __device__ __forceinline__

static constexpr int Bn  = 2;
static constexpr int S   = 2048;
static constexpr int DIM = 1024;
static constexpr int NH  = 16;
static constexpr int HD  = 64;
static constexpr int Mrows = Bn * S;        // 4096

DEVFN f32x4 mfma16(bf16x8 a, bf16x8 b, f32x4 c) {
  return __builtin_amdgcn_mfma_f32_16x16x32_bf16(a, b, c, 0, 0, 0);
}

DEVFN void gl_lds16(const bf16_t* g, bf16_t* l) {
  __builtin_amdgcn_global_load_lds(
      (const __attribute__((address_space(1))) unsigned*)g,
      (__attribute__((address_space(3))) unsigned*)l, 16, 0, 0);
}

// ---------------------------------------------------------------------------
// One launch: all fp32->bf16 converts + rope table.
// blocks 0..4095: x (1024 elems each); 4096..8191: weights (4 x 1024 blocks);
// 8192..8447: tab (65536 float2).
__global__ __launch_bounds__(256) void k_prep(
    const float* __restrict__ x, const float* __restrict__ wq,
    const float* __restrict__ wk, const float* __restrict__ wv,
    const float* __restrict__ wo, bf16_t* __restrict__ xb,
    bf16_t* __restrict__ wqb, bf16_t* __restrict__ wkb,
    bf16_t* __restrict__ wvb, bf16_t* __restrict__ wob,
    float2* __restrict__ tab) {
  const int bid = blockIdx.x;
  if (bid < 8192) {
    const float* src;
    bf16_t* dst;
    size_t base;
    if (bid < 4096) {
      src = x; dst = xb; base = (size_t)bid << 10;
    } else {
      int wsel = (bid - 4096) >> 10;
      src = wsel == 0 ? wq : wsel == 1 ? wk : wsel == 2 ? wv : wo;
      dst = wsel == 0 ? wqb : wsel == 1 ? wkb : wsel == 2 ? wvb : wob;
      base = (size_t)((bid - 4096) & 1023) << 10;
    }
    size_t i = base + (size_t)threadIdx.x * 4;
    float4 v = *(const float4*)(src + i);
    bf16x4 o = { (bf16_t)v.x, (bf16_t)v.y, (bf16_t)v.z, (bf16_t)v.w };
    *(bf16x4*)(dst + i) = o;
  } else {
    int i = (bid - 8192) * 256 + threadIdx.x;  // < S*32
    int s = i >> 5, d = i & 31;
    float th = (float)s * expf((float)d * -0.2878231366f);  // ln(10000)/32
    tab[i] = make_float2(cosf(th), sinf(th));
  }
}

// ---------------------------------------------------------------------------
// Fused QKV NT GEMM: 128x128 tile, BK=32, 4 waves x (4x4) 16x16x32 MFMA.
// z=0 -> Q (rope, scale 1/8), z=1 -> K (rope), z=2 -> V (transposed to VT).
__global__ __launch_bounds__(256) void k_gemm_qkv(
    const bf16_t* __restrict__ A, const bf16_t* __restrict__ B0,
    const bf16_t* __restrict__ B1, const bf16_t* __restrict__ B2,
    const float* __restrict__ c0, const float* __restrict__ c1,
    const float* __restrict__ c2, bf16_t* __restrict__ Oq,
    bf16_t* __restrict__ Ok, bf16_t* __restrict__ VTo,
    const float2* __restrict__ tab) {
  const int z = blockIdx.z;
  const bf16_t* Bw = z == 0 ? B0 : (z == 1 ? B1 : B2);
  const float* bias = z == 0 ? c0 : (z == 1 ? c1 : c2);

  __shared__ __align__(16) bf16_t Al[128 * 32];
  __shared__ __align__(16) bf16_t Bl[128 * 32];
  const int t = threadIdx.x, w = t >> 6, l = t & 63;
  const int lr = l & 15, lc = l >> 4;
  const int m0 = blockIdx.y * 128, n0 = blockIdx.x * 128;
  const int wr = w >> 1, wc = w & 1;
  f32x4 acc[4][4] = {};

  for (int k0 = 0; k0 < DIM; k0 += 32) {
    __syncthreads();
#pragma unroll
    for (int ld = 0; ld < 2; ++ld) {
      int c = t + ld * 256;
      int row = c >> 2, j = (c & 3) << 3;
      bf16_t* dstA = Al + (size_t)(w * 64 + ld * 256) * 8;
      bf16_t* dstB = Bl + (size_t)(w * 64 + ld * 256) * 8;
      gl_lds16(A + (size_t)(m0 + row) * DIM + k0 + j, dstA);
      gl_lds16(Bw + (size_t)(n0 + row) * DIM + k0 + j, dstB);
    }
    __syncthreads();
    bf16x8 af[4], bfr[4];
#pragma unroll
    for (int mi = 0; mi < 4; ++mi)
      af[mi] = *(const bf16x8*)(Al + (wr * 64 + mi * 16 + lr) * 32 + lc * 8);
#pragma unroll
    for (int ni = 0; ni < 4; ++ni)
      bfr[ni] = *(const bf16x8*)(Bl + (wc * 64 + ni * 16 + lr) * 32 + lc * 8);
#pragma unroll
    for (int mi = 0; mi < 4; ++mi)
#pragma unroll
      for (int ni = 0; ni < 4; ++ni)
        acc[mi][ni] = mfma16(af[mi], bfr[ni], acc[mi][ni]);
  }

  if (z == 2) {
    // V: bias + transposed store VT[bh][d][s], 4 consecutive s per bf16x4
    const int h = (n0 >> 6) + wc;
#pragma unroll
    for (int ni = 0; ni < 4; ++ni) {
      const int d = ni * 16 + lr;
      const float bv = bias[n0 + wc * 64 + ni * 16 + lr];
#pragma unroll
      for (int mi = 0; mi < 4; ++mi) {
        int rowb = m0 + wr * 64 + mi * 16 + lc * 4;
        int bb = rowb >> 11, ss = rowb & (S - 1);
        bf16x4 pb = { (bf16_t)(acc[mi][ni][0] + bv),
                      (bf16_t)(acc[mi][ni][1] + bv),
                      (bf16_t)(acc[mi][ni][2] + bv),
                      (bf16_t)(acc[mi][ni][3] + bv) };
        *(bf16x4*)(VTo + ((size_t)(bb * NH + h) * HD + d) * S + ss) = pb;
      }
    }
  } else {
    // Q/K: bias + rope. Pair partner lives in adjacent lr lane.
    bf16_t* Ov = z == 0 ? Oq : Ok;
    const float scale = z == 0 ? 0.125f : 1.0f;
#pragma unroll
    for (int ni = 0; ni < 4; ++ni) {
      const int col = n0 + wc * 64 + ni * 16 + lr;
      const float bv = bias[col];
      const int p0 = ni * 8 + (lr >> 1);
#pragma unroll
      for (int mi = 0; mi < 4; ++mi) {
#pragma unroll
        for (int r = 0; r < 4; ++r) {
          int row = m0 + wr * 64 + mi * 16 + lc * 4 + r;
          float v = acc[mi][ni][r] + bv;
          float pt = __shfl_xor(v, 1);
          float2 cs = tab[(row & (S - 1)) * 32 + p0];
          float out = (lr & 1) ? (pt * cs.y + v * cs.x)
                               : (v * cs.x - pt * cs.y);
          Ov[(size_t)row * DIM + col] = (bf16_t)(out * scale);
        }
      }
    }
  }
}

// ---------------------------------------------------------------------------
// Out projection: 128x128 tile NT GEMM, fp32 out + bias.
__global__ __launch_bounds__(256) void k_gemm_out(
    const bf16_t* __restrict__ A, const bf16_t* __restrict__ Bw,
    const float* __restrict__ bias, float* __restrict__ Ov) {
  __shared__ __align__(16) bf16_t Al[128 * 32];
  __shared__ __align__(16) bf16_t Bl[128 * 32];
  const int t = threadIdx.x, w = t >> 6, l = t & 63;
  const int lr = l & 15, lc = l >> 4;
  const int m0 = blockIdx.y * 128, n0 = blockIdx.x * 128;
  const int wr = w >> 1, wc = w & 1;
  f32x4 acc[4][4] = {};

  for (int k0 = 0; k0 < DIM; k0 += 32) {
    __syncthreads();
#pragma unroll
    for (int ld = 0; ld < 2; ++ld) {
      int c = t + ld * 256;
      int row = c >> 2, j = (c & 3) << 3;
      bf16_t* dstA = Al + (size_t)(w * 64 + ld * 256) * 8;
      bf16_t* dstB = Bl + (size_t)(w * 64 + ld * 256) * 8;
      gl_lds16(A + (size_t)(m0 + row) * DIM + k0 + j, dstA);
      gl_lds16(Bw + (size_t)(n0 + row) * DIM + k0 + j, dstB);
    }
    __syncthreads();
    bf16x8 af[4], bfr[4];
#pragma unroll
    for (int mi = 0; mi < 4; ++mi)
      af[mi] = *(const bf16x8*)(Al + (wr * 64 + mi * 16 + lr) * 32 + lc * 8);
#pragma unroll
    for (int ni = 0; ni < 4; ++ni)
      bfr[ni] = *(const bf16x8*)(Bl + (wc * 64 + ni * 16 + lr) * 32 + lc * 8);
#pragma unroll
    for (int mi = 0; mi < 4; ++mi)
#pragma unroll
      for (int ni = 0; ni < 4; ++ni)
        acc[mi][ni] = mfma16(af[mi], bfr[ni], acc[mi][ni]);
  }

#pragma unroll
  for (int ni = 0; ni < 4; ++ni) {
    int col = n0 + wc * 64 + ni * 16 + lr;
    float bv = bias[col];
#pragma unroll
    for (int mi = 0; mi < 4; ++mi)
#pragma unroll
      for (int r = 0; r < 4; ++r) {
        int row = m0 + wr * 64 + mi * 16 + lc * 4 + r;
        Ov[(size_t)row * DIM + col] = acc[mi][ni][r] + bv;
      }
  }
}

// ---------------------------------------------------------------------------
// Causal flash attention, R5: in-wave pipelined.
// Paired q-tiles (a, 31-a): uniform 33 KV iterations. Swapped QK^T
// (s = mfma(K,Q)): lane (lr,lc) holds S[q=w*16+lr][k=ni*16+lc*4+r].
// s double-buffered in regs (sA/sB, static indexing); QKT(t+1) issued before
// softmax(t) so MFMA overlaps VALU. K dbuf + V tri-buf in LDS via
// global_load_lds (pre-swizzled source), stage(t+2) issued at iteration top,
// counted vmcnt(4). XCD remap: 4 heads per XCD -> K/V L2-resident.
DEVFN void stage_kv(const bf16_t* __restrict__ Kc,
                    const bf16_t* __restrict__ VT, bf16_t* Kb, bf16_t* Vb,
                    int b, int bh, int h, int k0, int tid, int w) {
#pragma unroll
  for (int ld = 0; ld < 2; ++ld) {
    int c = tid + ld * 256;
    int row = c >> 3;
    int j = ((c & 7) ^ (row & 7)) << 3;  // pre-swizzled source chunk
    bf16_t* dstK = Kb + (size_t)(w * 64 + ld * 256) * 8;
    bf16_t* dstV = Vb + (size_t)(w * 64 + ld * 256) * 8;
    gl_lds16(Kc + (size_t)(b * S + k0 + row) * DIM + h * HD + j, dstK);
    gl_lds16(VT + ((size_t)bh * HD + row) * S + k0 + j, dstV);
  }
}

__global__ __launch_bounds__(256) void k_attn(const bf16_t* __restrict__ Q,
                                              const bf16_t* __restrict__ Kc,
                                              const bf16_t* __restrict__ VT,
                                              bf16_t* __restrict__ O) {
  __shared__ __align__(16) bf16_t Kl[2][64 * 64];
  __shared__ __align__(16) bf16_t Vl[3][64 * 64];
  __shared__ __align__(16) bf16_t Pl[4][16 * 64];
  const int tid = threadIdx.x, w = tid >> 6, l = tid & 63;
  const int lr = l & 15, lc = l >> 4;
  const int lid = blockIdx.x + (blockIdx.y << 4);
  const int xcd = lid & 7, slot = lid >> 3;
  const int bh = xcd * 4 + (slot >> 4);
  const int a = slot & 15;
  const int b = bh >> 4, h = bh & 15;
  char* Pw = (char*)&Pl[w][0];

#pragma unroll 1
  for (int pi = 0; pi < 2; ++pi) {
    const int tile = (pi == 0) ? a : 31 - a;
    const int q0 = tile * 64;
    const int nt = tile + 1;

    bf16x8 qf[2];
    {
      const bf16_t* qp =
          Q + (size_t)(b * S + q0 + w * 16 + lr) * DIM + h * HD + lc * 8;
      qf[0] = *(const bf16x8*)qp;
      qf[1] = *(const bf16x8*)(qp + 32);
    }
    f32x4 o[4] = {};
    f32x4 sA[4], sB[4];
    float m_run = -INFINITY;
    float rowsum = 0.f;

    auto qkt = [&](f32x4(&sd)[4], const bf16_t* Kb) {
#pragma unroll
      for (int ni = 0; ni < 4; ++ni) sd[ni] = f32x4{0.f, 0.f, 0.f, 0.f};
      __builtin_amdgcn_s_setprio(1);
#pragma unroll
      for (int ks = 0; ks < 2; ++ks)
#pragma unroll
        for (int ni = 0; ni < 4; ++ni) {
          int row = ni * 16 + lr;
          int off = (ks * 64 + lc * 16) ^ ((row & 7) << 4);
          bf16x8 kf = *(const bf16x8*)((const char*)Kb + row * 128 + off);
          sd[ni] = mfma16(kf, qf[ks], sd[ni]);
        }
      __builtin_amdgcn_s_setprio(0);
    };

    // prologue: stage tiles 0 (and 1), wait tile 0, QKT(0) -> sA
    stage_kv(Kc, VT, &Kl[0][0], &Vl[0][0], b, bh, h, 0, tid, w);
    if (nt > 1) {
      stage_kv(Kc, VT, &Kl[1][0], &Vl[1][0], b, bh, h, 64, tid, w);
      asm volatile("s_waitcnt vmcnt(4)" ::: "memory");
    } else {
      asm volatile("s_waitcnt vmcnt(0)" ::: "memory");
    }
    __builtin_amdgcn_s_barrier();
    __builtin_amdgcn_sched_barrier(0);
    qkt(sA, &Kl[0][0]);
    __builtin_amdgcn_s_barrier();  // all waves' QKT(0) reads done before
                                   // body(0) can stage into Kl[0]

    auto body = [&](f32x4(&scur)[4], f32x4(&snxt)[4], int t) {
      if (t + 2 < nt)
        stage_kv(Kc, VT, &Kl[(t + 2) & 1][0], &Vl[(t + 2) % 3][0], b, bh, h,
                 (t + 2) * 64, tid, w);
      if (t + 1 < nt) {
        if (t + 2 < nt)
          asm volatile("s_waitcnt vmcnt(4)" ::: "memory");
        else
          asm volatile("s_waitcnt vmcnt(0)" ::: "memory");
        __builtin_amdgcn_s_barrier();
        __builtin_amdgcn_sched_barrier(0);
        qkt(snxt, &Kl[(t + 1) & 1][0]);   // overlaps softmax(scur) below
      }

      if (t == nt - 1) {  // diagonal: mask k_local > q_local
        const int qloc = w * 16 + lr;
#pragma unroll
        for (int ni = 0; ni < 4; ++ni)
#pragma unroll
          for (int r = 0; r < 4; ++r)
            if (ni * 16 + lc * 4 + r > qloc) scur[ni][r] = -INFINITY;
      }

      float pm = scur[0][0];
#pragma unroll
      for (int ni = 0; ni < 4; ++ni)
#pragma unroll
        for (int r = 0; r < 4; ++r) pm = fmaxf(pm, scur[ni][r]);
      pm = fmaxf(pm, __shfl_xor(pm, 16));
      pm = fmaxf(pm, __shfl_xor(pm, 32));

      if (__ballot(pm > m_run + 8.f)) {  // defer-max THR=8
        float mn = fmaxf(m_run, pm);
        float alpha = __expf(m_run - mn);
        m_run = mn;
        rowsum *= alpha;
#pragma unroll
        for (int r = 0; r < 4; ++r) {
          float aq = __shfl(alpha, lc * 4 + r);
#pragma unroll
          for (int ni = 0; ni < 4; ++ni) o[ni][r] *= aq;
        }
      }

      float rs = 0.f;
#pragma unroll
      for (int ni = 0; ni < 4; ++ni) {
        float p0 = __expf(scur[ni][0] - m_run);
        float p1 = __expf(scur[ni][1] - m_run);
        float p2 = __expf(scur[ni][2] - m_run);
        float p3 = __expf(scur[ni][3] - m_run);
        rs += (p0 + p1) + (p2 + p3);
        bf16x4 pb = { (bf16_t)p0, (bf16_t)p1, (bf16_t)p2, (bf16_t)p3 };
        *(bf16x4*)(Pw + (lr * 128 + ((ni * 32 + lc * 8) ^ ((lr & 7) << 4)))) =
            pb;
      }
      rs += __shfl_xor(rs, 16);
      rs += __shfl_xor(rs, 32);
      rowsum += rs;

      const bf16_t* Vb = &Vl[t % 3][0];
      __builtin_amdgcn_s_setprio(1);
#pragma unroll
      for (int ks = 0; ks < 2; ++ks) {
        int off = ks * 64 + lc * 16;
        bf16x8 pa = *(const bf16x8*)(Pw + lr * 128 + (off ^ ((lr & 7) << 4)));
#pragma unroll
        for (int ni = 0; ni < 4; ++ni) {
          int vrow = ni * 16 + lr;
          bf16x8 vb = *(const bf16x8*)((const char*)Vb + vrow * 128 +
                                       (off ^ ((vrow & 7) << 4)));
          o[ni] = mfma16(pa, vb, o[ni]);
        }
      }
      __builtin_amdgcn_s_setprio(0);

      __builtin_amdgcn_s_barrier();  // PV/QKT reads done before next overwrite
    };

#pragma unroll 1
    for (int t = 0; t < nt; ++t) {
      if (t & 1)
        body(sB, sA, t);
      else
        body(sA, sB, t);
    }

    float inv[4];
#pragma unroll
    for (int r = 0; r < 4; ++r) inv[r] = 1.0f / __shfl(rowsum, lc * 4 + r);
#pragma unroll
    for (int ni = 0; ni < 4; ++ni)
#pragma unroll
      for (int r = 0; r < 4; ++r) {
        int qr = q0 + w * 16 + lc * 4 + r;
        float v = o[ni][r] * inv[r];
        O[(size_t)(b * S + qr) * DIM + h * HD + ni * 16 + lr] = (bf16_t)v;
      }
  }
}

// ---------------------------------------------------------------------------
extern "C" void kernel_launch(void* const* d_in, const int* in_sizes, int n_in,
                              void* d_out, int out_size, void* d_ws,
                              size_t ws_size, hipStream_t stream) {
  const float* x  = (const float*)d_in[0];
  const float* wq = (const float*)d_in[1];
  const float* bq = (const float*)d_in[2];
  const float* wk = (const float*)d_in[3];
  const float* bk = (const float*)d_in[4];
  const float* wv = (const float*)d_in[5];
  const float* bv = (const float*)d_in[6];
  const float* wo = (const float*)d_in[7];
  const float* bo = (const float*)d_in[8];

  const size_t MD = (size_t)Mrows * DIM;   // 4194304
  const size_t WD = (size_t)DIM * DIM;     // 1048576
  bf16_t* W = (bf16_t*)d_ws;
  bf16_t* x_bf  = W;
  bf16_t* wq_bf = x_bf + MD;
  bf16_t* wk_bf = wq_bf + WD;
  bf16_t* wv_bf = wk_bf + WD;
  bf16_t* wo_bf = wv_bf + WD;
  bf16_t* q_lin = wo_bf + WD;
  bf16_t* k_lin = q_lin + MD;
  bf16_t* attn_out = k_lin + MD;
  bf16_t* vT    = attn_out + MD;
  float2* tab   = (float2*)(vT + MD);

  k_prep<<<8448, 256, 0, stream>>>(x, wq, wk, wv, wo, x_bf, wq_bf, wk_bf,
                                   wv_bf, wo_bf, tab);

  k_gemm_qkv<<<dim3(DIM / 128, Mrows / 128, 3), 256, 0, stream>>>(
      x_bf, wq_bf, wk_bf, wv_bf, bq, bk, bv, q_lin, k_lin, vT, tab);

  k_attn<<<dim3(16, Bn * NH), 256, 0, stream>>>(q_lin, k_lin, vT, attn_out);

  k_gemm_out<<<dim3(DIM / 128, Mrows / 128), 256, 0, stream>>>(
      attn_out, wo_bf, bo, (float*)d_out);
}